// Round 1
// baseline (120.979 us; speedup 1.0000x reference)
//
#include <hip/hip_runtime.h>
#include <hip/hip_fp16.h>

typedef __attribute__((ext_vector_type(8))) _Float16 half8;

#define DIM 256
#define NN  384
#define BB  4

// ---------------- K0: transpose Wx [e][d] -> WxT [d][e] ----------------
__global__ __launch_bounds__(256) void k_transpose(const float* __restrict__ W,
                                                   float* __restrict__ WT) {
    __shared__ float t[32][33];
    const int bx = blockIdx.x & 7, by = blockIdx.x >> 3;
    const int tx = threadIdx.x & 31, ty = threadIdx.x >> 5; // ty 0..7
#pragma unroll
    for (int k = 0; k < 4; k++) {
        const int r = ty + k * 8;
        t[r][tx] = W[(by * 32 + r) * DIM + bx * 32 + tx];
    }
    __syncthreads();
#pragma unroll
    for (int k = 0; k < 4; k++) {
        const int r = ty + k * 8;
        WT[(bx * 32 + r) * DIM + by * 32 + tx] = t[tx][r];
    }
}

// ---------------- K1: xp = x @ Wx^T + bx ; emit fp16 xp and xp+bi ------
// 6 rows per block -> 256 blocks. x reads are wave-uniform -> s_load;
// WxT reads are lane-coalesced.
#define ROWS 6
__global__ __launch_bounds__(256) void k_proj(const float* __restrict__ x,
                                              const float* __restrict__ WxT,
                                              const float* __restrict__ bx,
                                              const float* __restrict__ bi,
                                              __half* __restrict__ xph,
                                              __half* __restrict__ xpbh) {
    const int row0 = blockIdx.x * ROWS;
    const int e = threadIdx.x;
    float acc[ROWS];
    const float b0 = bx[e];
#pragma unroll
    for (int r = 0; r < ROWS; r++) acc[r] = b0;
    const float* xr = x + (size_t)row0 * DIM;
    for (int d = 0; d < DIM; d += 4) {
        const float w0 = WxT[(d + 0) * DIM + e];
        const float w1 = WxT[(d + 1) * DIM + e];
        const float w2 = WxT[(d + 2) * DIM + e];
        const float w3 = WxT[(d + 3) * DIM + e];
#pragma unroll
        for (int r = 0; r < ROWS; r++) {
            const float4 xv = *(const float4*)(xr + r * DIM + d); // uniform -> s_load_dwordx4
            acc[r] = fmaf(xv.x, w0, acc[r]);
            acc[r] = fmaf(xv.y, w1, acc[r]);
            acc[r] = fmaf(xv.z, w2, acc[r]);
            acc[r] = fmaf(xv.w, w3, acc[r]);
        }
    }
    const float biv = bi[e];
#pragma unroll
    for (int r = 0; r < ROWS; r++) {
        xph [(size_t)(row0 + r) * DIM + e] = __float2half(acc[r]);
        xpbh[(size_t)(row0 + r) * DIM + e] = __float2half(acc[r] + biv);
    }
}

// ---------------- K2: out[b,i,j] = sigmoid( sum_d relu(...) * Ws + bs ) -
// 32x32 pair tile / block; 2x2 register tile / thread with i in {il,il+16},
// j in {jl,jl+16} so each wave reads 16 *consecutive* LDS rows -> 2-way
// bank aliasing (free). fp16 rows in LDS: one ds_read_b128 = 8 d's.
#define LDW 264  // halfs per LDS row: 256 + 8 pad (528 B, 16B-divisible)
__global__ __launch_bounds__(256) void k_main(const __half* __restrict__ xpbh,
                                              const __half* __restrict__ xph,
                                              const float* __restrict__ inc,
                                              const float* __restrict__ Wi,
                                              const float* __restrict__ Ws,
                                              const float* __restrict__ bs,
                                              float* __restrict__ out) {
    __shared__ __half xi[32][LDW]; // xp[i] + bi
    __shared__ __half xj[32][LDW]; // xp[j]
    const int blk = blockIdx.x;           // 576 = 4 * 12 * 12
    const int jt = blk % 12;
    const int it = (blk / 12) % 12;
    const int b  = blk / 144;
    const int i0 = it * 32, j0 = jt * 32;
    const int t  = threadIdx.x;
    const int il = t >> 4, jl = t & 15;   // 16 x 16 threads

    const __half* gi = xpbh + (size_t)(b * NN + i0) * DIM;
    const __half* gj = xph  + (size_t)(b * NN + j0) * DIM;
    for (int idx = t; idx < 32 * 32; idx += 256) { // 32 rows x 32 16B-chunks
        const int r = idx >> 5, c = (idx & 31) * 8;
        *(float4*)(&xi[r][c]) = *(const float4*)(gi + r * DIM + c);
        *(float4*)(&xj[r][c]) = *(const float4*)(gj + r * DIM + c);
    }
    __syncthreads();

    const float* incp = inc + ((size_t)(b * NN) + i0 + il) * NN + j0 + jl;
    const float i00 = incp[0];
    const float i01 = incp[16];
    const float i10 = incp[16 * NN];
    const float i11 = incp[16 * NN + 16];
    float a00 = 0.f, a01 = 0.f, a10 = 0.f, a11 = 0.f;

    for (int d = 0; d < DIM; d += 8) {
        const half8 hi0 = *(const half8*)(&xi[il][d]);
        const half8 hi1 = *(const half8*)(&xi[il + 16][d]);
        const half8 hj0 = *(const half8*)(&xj[jl][d]);
        const half8 hj1 = *(const half8*)(&xj[jl + 16][d]);
#pragma unroll
        for (int k = 0; k < 8; k++) {
            const float wik = Wi[d + k]; // uniform -> s_load
            const float wsk = Ws[d + k]; // uniform -> s_load
            const float fi0 = (float)hi0[k], fi1 = (float)hi1[k];
            const float fj0 = (float)hj0[k], fj1 = (float)hj1[k];
            float t00 = fmaf(i00, wik, fi0 + fj0);
            float t01 = fmaf(i01, wik, fi0 + fj1);
            float t10 = fmaf(i10, wik, fi1 + fj0);
            float t11 = fmaf(i11, wik, fi1 + fj1);
            t00 = fmaxf(t00, 0.f); t01 = fmaxf(t01, 0.f);
            t10 = fmaxf(t10, 0.f); t11 = fmaxf(t11, 0.f);
            a00 = fmaf(t00, wsk, a00); a01 = fmaf(t01, wsk, a01);
            a10 = fmaf(t10, wsk, a10); a11 = fmaf(t11, wsk, a11);
        }
    }
    const float bsv = bs[0];
    float* op = out + ((size_t)(b * NN) + i0 + il) * NN + j0 + jl;
    op[0]           = 1.f / (1.f + __expf(-(a00 + bsv)));
    op[16]          = 1.f / (1.f + __expf(-(a01 + bsv)));
    op[16 * NN]     = 1.f / (1.f + __expf(-(a10 + bsv)));
    op[16 * NN + 16]= 1.f / (1.f + __expf(-(a11 + bsv)));
}

extern "C" void kernel_launch(void* const* d_in, const int* in_sizes, int n_in,
                              void* d_out, int out_size, void* d_ws, size_t ws_size,
                              hipStream_t stream) {
    const float* x   = (const float*)d_in[0]; // [B,N,DIM]
    const float* inc = (const float*)d_in[1]; // [B,N,N]
    const float* Wx  = (const float*)d_in[2]; // [DIM,DIM]
    const float* bx  = (const float*)d_in[3]; // [DIM]
    const float* Wi  = (const float*)d_in[4]; // [DIM]
    const float* bi  = (const float*)d_in[5]; // [DIM]
    const float* Ws  = (const float*)d_in[6]; // [DIM]
    const float* bs  = (const float*)d_in[7]; // [1]
    float* out = (float*)d_out;

    char* ws = (char*)d_ws;
    float*  WxT  = (float*)ws;                        // 262,144 B
    __half* xph  = (__half*)(ws + 262144);            // 786,432 B
    __half* xpbh = (__half*)(ws + 262144 + 786432);   // 786,432 B (total 1.75 MB)

    k_transpose<<<64,  256, 0, stream>>>(Wx, WxT);
    k_proj     <<<256, 256, 0, stream>>>(x, WxT, bx, bi, xph, xpbh);
    k_main     <<<576, 256, 0, stream>>>(xpbh, xph, inc, Wi, Ws, bs, out);
}

// Round 3
// 96.940 us; speedup vs baseline: 1.2480x; 1.2480x over previous
//
#include <hip/hip_runtime.h>
#include <hip/hip_fp16.h>

#define DIM 256
#define NN  384

typedef _Float16 v2h __attribute__((ext_vector_type(2)));

__device__ __forceinline__ float fdot2f(__half2 a, __half2 b, float c) {
    // v_dot2_f32_f16: fp16 pair dot-product, fp32 accumulate
    return __builtin_amdgcn_fdot2(__builtin_bit_cast(v2h, a),
                                  __builtin_bit_cast(v2h, b), c, false);
}

// packed relu: max(a, 0) lane-wise on fp16 pair -> v_pk_max_f16
__device__ __forceinline__ __half2 relu2(__half2 a) {
    v2h av = __builtin_bit_cast(v2h, a);
#if __has_builtin(__builtin_elementwise_max)
    v2h zv = {(_Float16)0.0f, (_Float16)0.0f};
    v2h rv = __builtin_elementwise_max(av, zv);
#else
    v2h rv;
    rv.x = av.x > (_Float16)0.0f ? av.x : (_Float16)0.0f;
    rv.y = av.y > (_Float16)0.0f ? av.y : (_Float16)0.0f;
#endif
    return __builtin_bit_cast(__half2, rv);
}

// ---------------- K0: transpose Wx [e][d] -> WxT [d][e]; pack Wi/Ws fp16 ---
__global__ __launch_bounds__(256) void k_transpose(const float* __restrict__ W,
                                                   float* __restrict__ WT,
                                                   const float* __restrict__ Wi,
                                                   const float* __restrict__ Ws,
                                                   __half* __restrict__ wih,
                                                   __half* __restrict__ wsh) {
    __shared__ float t[32][33];
    const int bx = blockIdx.x & 7, by = blockIdx.x >> 3;
    const int tx = threadIdx.x & 31, ty = threadIdx.x >> 5; // ty 0..7
#pragma unroll
    for (int k = 0; k < 4; k++) {
        const int r = ty + k * 8;
        t[r][tx] = W[(by * 32 + r) * DIM + bx * 32 + tx];
    }
    if (blockIdx.x == 0) {
        wih[threadIdx.x] = __float2half(Wi[threadIdx.x]);
        wsh[threadIdx.x] = __float2half(Ws[threadIdx.x]);
    }
    __syncthreads();
#pragma unroll
    for (int k = 0; k < 4; k++) {
        const int r = ty + k * 8;
        WT[(bx * 32 + r) * DIM + by * 32 + tx] = t[tx][r];
    }
}

// ---------------- K1: xp = x @ Wx^T + bx ; emit fp16 xp and xp+bi ----------
// 4 rows/block -> 384 blocks (1.5 waves/SIMD). x rows staged in LDS
// (broadcast reads); WxT loads coalesced, double-buffered to hide L2 latency.
#define PR 4
__global__ __launch_bounds__(256) void k_proj(const float* __restrict__ x,
                                              const float* __restrict__ WxT,
                                              const float* __restrict__ bx,
                                              const float* __restrict__ bi,
                                              __half* __restrict__ xph,
                                              __half* __restrict__ xpbh) {
    __shared__ float xs[PR][DIM];
    const int row0 = blockIdx.x * PR;
    const int e = threadIdx.x;
    const float* xr = x + (size_t)row0 * DIM;
#pragma unroll
    for (int k = 0; k < PR; k++) xs[k][e] = xr[k * DIM + e];
    __syncthreads();

    float acc[PR];
    const float b0 = bx[e];
#pragma unroll
    for (int r = 0; r < PR; r++) acc[r] = b0;

    float w0 = WxT[0 * DIM + e];
    float w1 = WxT[1 * DIM + e];
    float w2 = WxT[2 * DIM + e];
    float w3 = WxT[3 * DIM + e];
    for (int d = 0; d < DIM; d += 4) {
        const int dn = (d + 4) & (DIM - 1); // wraps to 0 on last iter (harmless)
        const float n0 = WxT[(dn + 0) * DIM + e];
        const float n1 = WxT[(dn + 1) * DIM + e];
        const float n2 = WxT[(dn + 2) * DIM + e];
        const float n3 = WxT[(dn + 3) * DIM + e];
#pragma unroll
        for (int r = 0; r < PR; r++) {
            const float4 xv = *(const float4*)&xs[r][d]; // uniform -> LDS broadcast
            acc[r] = fmaf(xv.x, w0, acc[r]);
            acc[r] = fmaf(xv.y, w1, acc[r]);
            acc[r] = fmaf(xv.z, w2, acc[r]);
            acc[r] = fmaf(xv.w, w3, acc[r]);
        }
        w0 = n0; w1 = n1; w2 = n2; w3 = n3;
    }
    const float biv = bi[e];
#pragma unroll
    for (int r = 0; r < PR; r++) {
        xph [(size_t)(row0 + r) * DIM + e] = __float2half(acc[r]);
        xpbh[(size_t)(row0 + r) * DIM + e] = __float2half(acc[r] + biv);
    }
}

// ---------------- K2: out[b,i,j] = sigmoid( sum_d relu(...)*Ws + bs ) ------
// 32x32 pair tile/block; 2x2 reg tile/thread (i in {il,il+16}, j in {jl,jl+16}).
// Packed-f16 math: v_pk_add/fma/max + v_dot2_f32_f16 = 2 d's per instruction,
// fp32 accumulation. 16 inst per 2d per 2x2 tile (was 40).
#define LDW 264  // halfs per LDS row: 256 + 8 pad (528 B, 16B-divisible)
__global__ __launch_bounds__(256) void k_main(const __half* __restrict__ xpbh,
                                              const __half* __restrict__ xph,
                                              const float* __restrict__ inc,
                                              const __half* __restrict__ wih,
                                              const __half* __restrict__ wsh,
                                              const float* __restrict__ bs,
                                              float* __restrict__ out) {
    __shared__ __half xi[32][LDW]; // xp[i] + bi
    __shared__ __half xj[32][LDW]; // xp[j]
    const int blk = blockIdx.x;           // 576 = 4 * 12 * 12
    const int jt = blk % 12;
    const int it = (blk / 12) % 12;
    const int b  = blk / 144;
    const int i0 = it * 32, j0 = jt * 32;
    const int t  = threadIdx.x;
    const int il = t >> 4, jl = t & 15;   // 16 x 16 threads

    const __half* gi = xpbh + (size_t)(b * NN + i0) * DIM;
    const __half* gj = xph  + (size_t)(b * NN + j0) * DIM;
    for (int idx = t; idx < 32 * 32; idx += 256) { // 32 rows x 32 16B-chunks
        const int r = idx >> 5, c = (idx & 31) * 8;
        *(float4*)(&xi[r][c]) = *(const float4*)(gi + r * DIM + c);
        *(float4*)(&xj[r][c]) = *(const float4*)(gj + r * DIM + c);
    }
    __syncthreads();

    const float* incp = inc + ((size_t)(b * NN) + i0 + il) * NN + j0 + jl;
    const __half2 i00p = __float2half2_rn(incp[0]);
    const __half2 i01p = __float2half2_rn(incp[16]);
    const __half2 i10p = __float2half2_rn(incp[16 * NN]);
    const __half2 i11p = __float2half2_rn(incp[16 * NN + 16]);
    float a00 = 0.f, a01 = 0.f, a10 = 0.f, a11 = 0.f;

    const __half2* wih2 = (const __half2*)wih;
    const __half2* wsh2 = (const __half2*)wsh;

    union F4H { float4 f; __half2 h[4]; };
    for (int d = 0; d < DIM; d += 8) {
        F4H hi0, hi1, hj0, hj1;
        hi0.f = *(const float4*)&xi[il][d];
        hi1.f = *(const float4*)&xi[il + 16][d];
        hj0.f = *(const float4*)&xj[jl][d];
        hj1.f = *(const float4*)&xj[jl + 16][d];
#pragma unroll
        for (int k2 = 0; k2 < 4; k2++) {
            const __half2 wi2 = wih2[(d >> 1) + k2]; // uniform -> s_load
            const __half2 ws2 = wsh2[(d >> 1) + k2]; // uniform -> s_load
            __half2 s00 = __hadd2(hi0.h[k2], hj0.h[k2]);
            __half2 s01 = __hadd2(hi0.h[k2], hj1.h[k2]);
            __half2 s10 = __hadd2(hi1.h[k2], hj0.h[k2]);
            __half2 s11 = __hadd2(hi1.h[k2], hj1.h[k2]);
            s00 = __hfma2(i00p, wi2, s00);
            s01 = __hfma2(i01p, wi2, s01);
            s10 = __hfma2(i10p, wi2, s10);
            s11 = __hfma2(i11p, wi2, s11);
            s00 = relu2(s00);
            s01 = relu2(s01);
            s10 = relu2(s10);
            s11 = relu2(s11);
            a00 = fdot2f(s00, ws2, a00);
            a01 = fdot2f(s01, ws2, a01);
            a10 = fdot2f(s10, ws2, a10);
            a11 = fdot2f(s11, ws2, a11);
        }
    }
    const float bsv = bs[0];
    float* op = out + ((size_t)(b * NN) + i0 + il) * NN + j0 + jl;
    op[0]            = 1.f / (1.f + __expf(-(a00 + bsv)));
    op[16]           = 1.f / (1.f + __expf(-(a01 + bsv)));
    op[16 * NN]      = 1.f / (1.f + __expf(-(a10 + bsv)));
    op[16 * NN + 16] = 1.f / (1.f + __expf(-(a11 + bsv)));
}

extern "C" void kernel_launch(void* const* d_in, const int* in_sizes, int n_in,
                              void* d_out, int out_size, void* d_ws, size_t ws_size,
                              hipStream_t stream) {
    const float* x   = (const float*)d_in[0]; // [B,N,DIM]
    const float* inc = (const float*)d_in[1]; // [B,N,N]
    const float* Wx  = (const float*)d_in[2]; // [DIM,DIM]
    const float* bx  = (const float*)d_in[3]; // [DIM]
    const float* Wi  = (const float*)d_in[4]; // [DIM]
    const float* bi  = (const float*)d_in[5]; // [DIM]
    const float* Ws  = (const float*)d_in[6]; // [DIM]
    const float* bs  = (const float*)d_in[7]; // [1]
    float* out = (float*)d_out;

    char* ws = (char*)d_ws;
    float*  WxT  = (float*)ws;                          // 262,144 B
    __half* xph  = (__half*)(ws + 262144);              // 786,432 B
    __half* xpbh = (__half*)(ws + 262144 + 786432);     // 786,432 B
    __half* wih  = (__half*)(ws + 262144 + 2 * 786432); // 512 B
    __half* wsh  = (__half*)(ws + 262144 + 2 * 786432 + 512);

    k_transpose<<<64,  256, 0, stream>>>(Wx, WxT, Wi, Ws, wih, wsh);
    k_proj     <<<384, 256, 0, stream>>>(x, WxT, bx, bi, xph, xpbh);
    k_main     <<<576, 256, 0, stream>>>(xpbh, xph, inc, wih, wsh, bs, out);
}

// Round 4
// 96.484 us; speedup vs baseline: 1.2539x; 1.0047x over previous
//
#include <hip/hip_runtime.h>
#include <hip/hip_fp16.h>

#define DIM 256
#define NN  384

typedef _Float16 v2h __attribute__((ext_vector_type(2)));

__device__ __forceinline__ float fdot2f(__half2 a, __half2 b, float c) {
    // v_dot2_f32_f16: fp16 pair dot-product, fp32 accumulate
    return __builtin_amdgcn_fdot2(__builtin_bit_cast(v2h, a),
                                  __builtin_bit_cast(v2h, b), c, false);
}

// packed relu: max(a, 0) lane-wise on fp16 pair -> v_pk_max_f16
__device__ __forceinline__ __half2 relu2(__half2 a) {
    v2h av = __builtin_bit_cast(v2h, a);
#if __has_builtin(__builtin_elementwise_max)
    v2h zv = {(_Float16)0.0f, (_Float16)0.0f};
    v2h rv = __builtin_elementwise_max(av, zv);
#else
    v2h rv;
    rv.x = av.x > (_Float16)0.0f ? av.x : (_Float16)0.0f;
    rv.y = av.y > (_Float16)0.0f ? av.y : (_Float16)0.0f;
#endif
    return __builtin_bit_cast(__half2, rv);
}

// ---------------- K0: transpose Wx [e][d] -> WxT [d][e]; pack Wi/Ws fp16 ---
__global__ __launch_bounds__(256) void k_transpose(const float* __restrict__ W,
                                                   float* __restrict__ WT,
                                                   const float* __restrict__ Wi,
                                                   const float* __restrict__ Ws,
                                                   __half* __restrict__ wih,
                                                   __half* __restrict__ wsh) {
    __shared__ float t[32][33];
    const int bx = blockIdx.x & 7, by = blockIdx.x >> 3;
    const int tx = threadIdx.x & 31, ty = threadIdx.x >> 5; // ty 0..7
#pragma unroll
    for (int k = 0; k < 4; k++) {
        const int r = ty + k * 8;
        t[r][tx] = W[(by * 32 + r) * DIM + bx * 32 + tx];
    }
    if (blockIdx.x == 0) {
        wih[threadIdx.x] = __float2half(Wi[threadIdx.x]);
        wsh[threadIdx.x] = __float2half(Ws[threadIdx.x]);
    }
    __syncthreads();
#pragma unroll
    for (int k = 0; k < 4; k++) {
        const int r = ty + k * 8;
        WT[(bx * 32 + r) * DIM + by * 32 + tx] = t[tx][r];
    }
}

// ---------------- K1: xp = x @ Wx^T + bx ; emit fp16 xp and xp+bi ----------
// 4 rows/block -> 384 blocks (1.5 waves/SIMD). x rows staged in LDS
// (broadcast reads); WxT loads coalesced, double-buffered to hide L2 latency.
#define PR 4
__global__ __launch_bounds__(256) void k_proj(const float* __restrict__ x,
                                              const float* __restrict__ WxT,
                                              const float* __restrict__ bx,
                                              const float* __restrict__ bi,
                                              __half* __restrict__ xph,
                                              __half* __restrict__ xpbh) {
    __shared__ float xs[PR][DIM];
    const int row0 = blockIdx.x * PR;
    const int e = threadIdx.x;
    const float* xr = x + (size_t)row0 * DIM;
#pragma unroll
    for (int k = 0; k < PR; k++) xs[k][e] = xr[k * DIM + e];
    __syncthreads();

    float acc[PR];
    const float b0 = bx[e];
#pragma unroll
    for (int r = 0; r < PR; r++) acc[r] = b0;

    float w0 = WxT[0 * DIM + e];
    float w1 = WxT[1 * DIM + e];
    float w2 = WxT[2 * DIM + e];
    float w3 = WxT[3 * DIM + e];
    for (int d = 0; d < DIM; d += 4) {
        const int dn = (d + 4) & (DIM - 1); // wraps to 0 on last iter (harmless)
        const float n0 = WxT[(dn + 0) * DIM + e];
        const float n1 = WxT[(dn + 1) * DIM + e];
        const float n2 = WxT[(dn + 2) * DIM + e];
        const float n3 = WxT[(dn + 3) * DIM + e];
#pragma unroll
        for (int r = 0; r < PR; r++) {
            const float4 xv = *(const float4*)&xs[r][d]; // uniform -> LDS broadcast
            acc[r] = fmaf(xv.x, w0, acc[r]);
            acc[r] = fmaf(xv.y, w1, acc[r]);
            acc[r] = fmaf(xv.z, w2, acc[r]);
            acc[r] = fmaf(xv.w, w3, acc[r]);
        }
        w0 = n0; w1 = n1; w2 = n2; w3 = n3;
    }
    const float biv = bi[e];
#pragma unroll
    for (int r = 0; r < PR; r++) {
        xph [(size_t)(row0 + r) * DIM + e] = __float2half(acc[r]);
        xpbh[(size_t)(row0 + r) * DIM + e] = __float2half(acc[r] + biv);
    }
}

// ---------------- K2: out[b,i,j] = sigmoid( sum_d relu(...)*Ws + bs ) ------
// 32x32 pair tile/block; 2x2 reg tile/thread (i in {il,il+16}, j in {jl,jl+16}).
// Packed-f16 math: 2 inst per (output,d) = the VALU floor for this algorithm
// (no cross-pair reuse exists: inc_ij*Wi_d is rank-1 per pair).
// d-loop fully unrolled: ds_read offsets become immediates, no loop overhead.
#define LDW 264  // halfs per LDS row: 256 + 8 pad (528 B, 16B-divisible)
__global__ __launch_bounds__(256) void k_main(const __half* __restrict__ xpbh,
                                              const __half* __restrict__ xph,
                                              const float* __restrict__ inc,
                                              const __half* __restrict__ wih,
                                              const __half* __restrict__ wsh,
                                              const float* __restrict__ bs,
                                              float* __restrict__ out) {
    __shared__ __half xi[32][LDW]; // xp[i] + bi
    __shared__ __half xj[32][LDW]; // xp[j]
    const int blk = blockIdx.x;           // 576 = 4 * 12 * 12
    const int jt = blk % 12;
    const int it = (blk / 12) % 12;
    const int b  = blk / 144;
    const int i0 = it * 32, j0 = jt * 32;
    const int t  = threadIdx.x;
    const int il = t >> 4, jl = t & 15;   // 16 x 16 threads

    // issue inc loads FIRST: latency hides under LDS staging + barrier
    const float* incp = inc + ((size_t)(b * NN) + i0 + il) * NN + j0 + jl;
    const float inc00 = incp[0];
    const float inc01 = incp[16];
    const float inc10 = incp[16 * NN];
    const float inc11 = incp[16 * NN + 16];
    const float bsv = bs[0];

    const __half* gi = xpbh + (size_t)(b * NN + i0) * DIM;
    const __half* gj = xph  + (size_t)(b * NN + j0) * DIM;
    for (int idx = t; idx < 32 * 32; idx += 256) { // 32 rows x 32 16B-chunks
        const int r = idx >> 5, c = (idx & 31) * 8;
        *(float4*)(&xi[r][c]) = *(const float4*)(gi + r * DIM + c);
        *(float4*)(&xj[r][c]) = *(const float4*)(gj + r * DIM + c);
    }
    __syncthreads();

    const __half2 i00p = __float2half2_rn(inc00);
    const __half2 i01p = __float2half2_rn(inc01);
    const __half2 i10p = __float2half2_rn(inc10);
    const __half2 i11p = __float2half2_rn(inc11);
    // fold bs into the accumulator init (kills 4 epilogue adds)
    float a00 = bsv, a01 = bsv, a10 = bsv, a11 = bsv;

    const __half2* wih2 = (const __half2*)wih;
    const __half2* wsh2 = (const __half2*)wsh;

    union F4H { float4 f; __half2 h[4]; };
#pragma unroll
    for (int d = 0; d < DIM; d += 8) {
        F4H hi0, hi1, hj0, hj1;
        hi0.f = *(const float4*)&xi[il][d];
        hi1.f = *(const float4*)&xi[il + 16][d];
        hj0.f = *(const float4*)&xj[jl][d];
        hj1.f = *(const float4*)&xj[jl + 16][d];
#pragma unroll
        for (int k2 = 0; k2 < 4; k2++) {
            const __half2 wi2 = wih2[(d >> 1) + k2]; // uniform -> s_load
            const __half2 ws2 = wsh2[(d >> 1) + k2]; // uniform -> s_load
            __half2 s00 = __hadd2(hi0.h[k2], hj0.h[k2]);
            __half2 s01 = __hadd2(hi0.h[k2], hj1.h[k2]);
            __half2 s10 = __hadd2(hi1.h[k2], hj0.h[k2]);
            __half2 s11 = __hadd2(hi1.h[k2], hj1.h[k2]);
            s00 = __hfma2(i00p, wi2, s00);
            s01 = __hfma2(i01p, wi2, s01);
            s10 = __hfma2(i10p, wi2, s10);
            s11 = __hfma2(i11p, wi2, s11);
            s00 = relu2(s00);
            s01 = relu2(s01);
            s10 = relu2(s10);
            s11 = relu2(s11);
            a00 = fdot2f(s00, ws2, a00);
            a01 = fdot2f(s01, ws2, a01);
            a10 = fdot2f(s10, ws2, a10);
            a11 = fdot2f(s11, ws2, a11);
        }
    }
    float* op = out + ((size_t)(b * NN) + i0 + il) * NN + j0 + jl;
    op[0]            = 1.f / (1.f + __expf(-a00));
    op[16]           = 1.f / (1.f + __expf(-a01));
    op[16 * NN]      = 1.f / (1.f + __expf(-a10));
    op[16 * NN + 16] = 1.f / (1.f + __expf(-a11));
}

extern "C" void kernel_launch(void* const* d_in, const int* in_sizes, int n_in,
                              void* d_out, int out_size, void* d_ws, size_t ws_size,
                              hipStream_t stream) {
    const float* x   = (const float*)d_in[0]; // [B,N,DIM]
    const float* inc = (const float*)d_in[1]; // [B,N,N]
    const float* Wx  = (const float*)d_in[2]; // [DIM,DIM]
    const float* bx  = (const float*)d_in[3]; // [DIM]
    const float* Wi  = (const float*)d_in[4]; // [DIM]
    const float* bi  = (const float*)d_in[5]; // [DIM]
    const float* Ws  = (const float*)d_in[6]; // [DIM]
    const float* bs  = (const float*)d_in[7]; // [1]
    float* out = (float*)d_out;

    char* ws = (char*)d_ws;
    float*  WxT  = (float*)ws;                          // 262,144 B
    __half* xph  = (__half*)(ws + 262144);              // 786,432 B
    __half* xpbh = (__half*)(ws + 262144 + 786432);     // 786,432 B
    __half* wih  = (__half*)(ws + 262144 + 2 * 786432); // 512 B
    __half* wsh  = (__half*)(ws + 262144 + 2 * 786432 + 512);

    k_transpose<<<64,  256, 0, stream>>>(Wx, WxT, Wi, Ws, wih, wsh);
    k_proj     <<<384, 256, 0, stream>>>(x, WxT, bx, bi, xph, xpbh);
    k_main     <<<576, 256, 0, stream>>>(xpbh, xph, inc, wih, wsh, bs, out);
}